// Round 1
// baseline (69.522 us; speedup 1.0000x reference)
//
#include <hip/hip_runtime.h>
#include <math.h>

#define HDIM 512
#define NROWS 100000

// ---- workspace layout (float indices) ----
constexpr int SIMS_OFF   = 0;                    // [100000] sims
constexpr int MIN_OFF    = NROWS;                // [1] int bits: min of ||K-cue||^2 (>=0)
constexpr int PREACT_OFF = NROWS + 1;            // [2560] Wx@x + Wh@h0 + b
constexpr int PM_OFF     = PREACT_OFF + 5*HDIM;  // [64*512] partial sum e*V
constexpr int PD_OFF     = PM_OFF + 64*HDIM;     // [64] partial sum e

__device__ __forceinline__ float wave_sum(float v) {
    #pragma unroll
    for (int off = 32; off; off >>= 1) v += __shfl_xor(v, off);
    return v;
}

// ---- kernel 1: preact[r] = Wx[r,:]@x + Wh[r,:]@h0 + b[r]; also init min slot ----
__global__ void k_preact(const float* __restrict__ state, const float* __restrict__ pa,
                         const float* __restrict__ pr, const float* __restrict__ ts,
                         const float* __restrict__ Wx, const float* __restrict__ Wh,
                         const float* __restrict__ b, const float* __restrict__ h0,
                         float* __restrict__ ws) {
    if (blockIdx.x == 0 && threadIdx.x == 0)
        ((int*)ws)[MIN_OFF] = 0x7F800000;  // +inf

    const int lane = threadIdx.x & 63;
    const int row  = blockIdx.x * 4 + (threadIdx.x >> 6);  // one wave per output row
    if (row >= 5 * HDIM) return;

    // x_t = concat(state[64], p_action[4], p_reward[1], timestep[1])  -> 70
    float x0 = state[lane];
    float x1 = 0.f;
    if      (lane < 4)  x1 = pa[lane];
    else if (lane == 4) x1 = pr[0];
    else if (lane == 5) x1 = ts[0];

    const float4* h04 = (const float4*)h0;
    const float4  hA = h04[lane], hB = h04[64 + lane];
    const float4* wh4 = (const float4*)(Wh + (size_t)row * HDIM);
    const float4  a0 = wh4[lane], a1 = wh4[64 + lane];

    float acc = a0.x*hA.x + a0.y*hA.y + a0.z*hA.z + a0.w*hA.w
              + a1.x*hB.x + a1.y*hB.y + a1.z*hB.z + a1.w*hB.w;

    const float* wxr = Wx + (size_t)row * 70;
    acc += wxr[lane] * x0;
    if (lane < 6) acc += wxr[64 + lane] * x1;

    acc = wave_sum(acc);
    if (lane == 0) ws[PREACT_OFF + row] = acc + b[row];
}

// ---- kernel 2: sims[n] = -||K[n]-cue||^2 ; global max via int atomicMin on negsim ----
__global__ void k_sims(const float* __restrict__ K, const float* __restrict__ cue,
                       float* __restrict__ ws) {
    const int lane = threadIdx.x & 63;
    const int wib  = threadIdx.x >> 6;
    const int gwid = blockIdx.x * 4 + wib;
    const int nw   = gridDim.x * 4;

    const float4* c4 = (const float4*)cue;
    const float4 cA = c4[lane], cB = c4[64 + lane];

    float minneg = INFINITY;
    for (int n = gwid; n < NROWS; n += nw) {
        const float4* k4 = (const float4*)(K + (size_t)n * HDIM);
        float4 kA = k4[lane], kB = k4[64 + lane];
        float d, ss;
        d = kA.x - cA.x; ss  = d*d;
        d = kA.y - cA.y; ss += d*d;
        d = kA.z - cA.z; ss += d*d;
        d = kA.w - cA.w; ss += d*d;
        d = kB.x - cB.x; ss += d*d;
        d = kB.y - cB.y; ss += d*d;
        d = kB.z - cB.z; ss += d*d;
        d = kB.w - cB.w; ss += d*d;
        ss = wave_sum(ss);                 // all lanes hold full sum
        if (lane == 0) ws[SIMS_OFF + n] = -ss;
        minneg = fminf(minneg, ss);
    }

    __shared__ float smin[4];
    if (lane == 0) smin[wib] = minneg;
    __syncthreads();
    if (threadIdx.x == 0) {
        float m = fminf(fminf(smin[0], smin[1]), fminf(smin[2], smin[3]));
        // non-negative floats: int compare == float compare; atomicMin is exact/deterministic
        atomicMin((int*)ws + MIN_OFF, __float_as_int(m));
    }
}

// ---- kernel 3: scan sims, gather V rows with exp(sims-max) >= exp(-30), exact denom ----
__global__ void k_gather(const float* __restrict__ V, float* __restrict__ ws) {
    const int lane = threadIdx.x & 63;
    const int w    = threadIdx.x >> 6;
    const int gwid = blockIdx.x * 4 + w;
    const int nw   = gridDim.x * 4;   // 256 waves

    const float smax = -__int_as_float(((const int*)ws)[MIN_OFF]);

    float4 accA = {0.f,0.f,0.f,0.f}, accB = {0.f,0.f,0.f,0.f};
    float dsum = 0.f;

    const int nchunks = (NROWS + 63) / 64;
    for (int c = gwid; c < nchunks; c += nw) {
        const int n = c * 64 + lane;
        const bool valid = (n < NROWS);
        const float s = valid ? ws[SIMS_OFF + n] : -INFINITY;
        const float e = expf(s - smax);        // underflows to 0 for far rows
        dsum += e;                              // exact denominator
        unsigned long long mask = __ballot(valid && (s - smax >= -30.0f));
        while (mask) {
            const int bpos = __ffsll(mask) - 1;
            mask &= mask - 1;
            const int nb = c * 64 + bpos;
            const float eb = __shfl(e, bpos);
            const float4* v4 = (const float4*)(V + (size_t)nb * HDIM);
            const float4 vA = v4[lane], vB = v4[64 + lane];
            accA.x += eb * vA.x; accA.y += eb * vA.y; accA.z += eb * vA.z; accA.w += eb * vA.w;
            accB.x += eb * vB.x; accB.y += eb * vB.y; accB.z += eb * vB.z; accB.w += eb * vB.w;
        }
    }
    dsum = wave_sum(dsum);

    __shared__ float lm[4][HDIM];
    __shared__ float ld[4];
    float* rowp = lm[w];
    rowp[lane*4 + 0]       = accA.x; rowp[lane*4 + 1]       = accA.y;
    rowp[lane*4 + 2]       = accA.z; rowp[lane*4 + 3]       = accA.w;
    rowp[256 + lane*4 + 0] = accB.x; rowp[256 + lane*4 + 1] = accB.y;
    rowp[256 + lane*4 + 2] = accB.z; rowp[256 + lane*4 + 3] = accB.w;
    if (lane == 0) ld[w] = dsum;
    __syncthreads();

    const int t = threadIdx.x;
    const float s0 = lm[0][t] + lm[1][t] + lm[2][t] + lm[3][t];
    const float s1 = lm[0][256+t] + lm[1][256+t] + lm[2][256+t] + lm[3][256+t];
    ws[PM_OFF + blockIdx.x * HDIM + t]       = s0;
    ws[PM_OFF + blockIdx.x * HDIM + 256 + t] = s1;
    if (t == 0) ws[PD_OFF + blockIdx.x] = ld[0] + ld[1] + ld[2] + ld[3];
}

// ---- kernel 4: reduce partials -> m_t; LSTM cell; actor/critic heads ----
__global__ void k_final(const float* __restrict__ c0, const float* __restrict__ aw,
                        const float* __restrict__ ab, const float* __restrict__ cw,
                        const float* __restrict__ cb, float* __restrict__ ws,
                        float* __restrict__ out) {
    const int t = threadIdx.x;       // 512 threads
    const int lane = t & 63;
    const int w = t >> 6;            // 8 waves

    __shared__ float hl[HDIM];
    __shared__ float sden;
    __shared__ float logits[4];

    if (w == 0) {
        float dsum = ws[PD_OFF + lane];
        dsum = wave_sum(dsum);
        if (lane == 0) sden = dsum;
    }
    float m = 0.f;
    #pragma unroll 8
    for (int b2 = 0; b2 < 64; b2++) m += ws[PM_OFF + b2 * HDIM + t];
    __syncthreads();
    m /= sden;

    const float pf = ws[PREACT_OFF + t];
    const float pi = ws[PREACT_OFF + HDIM + t];
    const float po = ws[PREACT_OFF + 2*HDIM + t];
    const float pr = ws[PREACT_OFF + 3*HDIM + t];
    const float pc = ws[PREACT_OFF + 4*HDIM + t];
    const float f_t = 1.f / (1.f + expf(-pf));
    const float i_t = 1.f / (1.f + expf(-pi));
    const float o_t = 1.f / (1.f + expf(-po));
    const float r_t = 1.f / (1.f + expf(-pr));
    const float chat = tanhf(pc);
    const float ct = f_t * c0[t] + i_t * chat + r_t * m;
    const float ht = o_t * tanhf(ct);
    out[517 + t] = ct;
    out[5 + t]   = ht;
    hl[t] = ht;
    __syncthreads();

    if (w < 4) {
        float acc = 0.f;
        #pragma unroll
        for (int j = 0; j < HDIM; j += 64) acc += aw[w * HDIM + lane + j] * hl[lane + j];
        acc = wave_sum(acc);
        if (lane == 0) logits[w] = acc + ab[w];
    } else if (w == 4) {
        float acc = 0.f;
        #pragma unroll
        for (int j = 0; j < HDIM; j += 64) acc += cw[lane + j] * hl[lane + j];
        acc = wave_sum(acc);
        if (lane == 0) out[4] = acc + cb[0];
    }
    __syncthreads();

    if (t == 0) {
        const float mx = fmaxf(fmaxf(logits[0], logits[1]), fmaxf(logits[2], logits[3]));
        const float e0 = expf(logits[0] - mx), e1 = expf(logits[1] - mx);
        const float e2 = expf(logits[2] - mx), e3 = expf(logits[3] - mx);
        const float inv = 1.f / (e0 + e1 + e2 + e3);
        out[0] = e0 * inv; out[1] = e1 * inv; out[2] = e2 * inv; out[3] = e3 * inv;
    }
}

extern "C" void kernel_launch(void* const* d_in, const int* in_sizes, int n_in,
                              void* d_out, int out_size, void* d_ws, size_t ws_size,
                              hipStream_t stream) {
    const float* state  = (const float*)d_in[0];
    const float* pa     = (const float*)d_in[1];
    const float* pr     = (const float*)d_in[2];
    const float* ts     = (const float*)d_in[3];
    const float* cue    = (const float*)d_in[4];
    const float* keys   = (const float*)d_in[5];
    const float* vals   = (const float*)d_in[6];
    const float* Wx     = (const float*)d_in[7];
    const float* Wh     = (const float*)d_in[8];
    const float* b      = (const float*)d_in[9];
    const float* aw     = (const float*)d_in[10];
    const float* ab     = (const float*)d_in[11];
    const float* cw     = (const float*)d_in[12];
    const float* cb     = (const float*)d_in[13];
    const float* h0     = (const float*)d_in[14];
    const float* c0     = (const float*)d_in[15];
    float* out = (float*)d_out;
    float* ws  = (float*)d_ws;

    k_preact<<<640, 256, 0, stream>>>(state, pa, pr, ts, Wx, Wh, b, h0, ws);
    k_sims<<<2048, 256, 0, stream>>>(keys, cue, ws);
    k_gather<<<64, 256, 0, stream>>>(vals, ws);
    k_final<<<1, 512, 0, stream>>>(c0, aw, ab, cw, cb, ws, out);
}